// Round 4
// baseline (5864.513 us; speedup 1.0000x reference)
//
#include <hip/hip_runtime.h>
#include <hip/hip_bf16.h>
#include <float.h>

#define NPTS 4096
#define NB 4
#define KNN 20

__device__ __forceinline__ float lrelu(float x) { return x > 0.f ? x : 0.2f * x; }

__device__ __forceinline__ void atomicMaxF(float* addr, float val) {
    int* ia = (int*)addr;
    int old = *ia;
    while (__int_as_float(old) < val) {
        int assumed = old;
        old = atomicCAS(ia, assumed, __float_as_int(val));
        if (old == assumed) break;
    }
}

// ---------------- sq norms for euclid knn (channel-major x, coalesced) ----------------
__global__ void k_sqnorm(const float* __restrict__ x, float* __restrict__ sq) {
    int i = blockIdx.x * 256 + threadIdx.x;   // b*N + n
    int b = i >> 12, n = i & 4095;
    const float* xb = x + b * 6 * NPTS;
    float s = 0.f;
#pragma unroll
    for (int c = 0; c < 6; c++) { float v = xb[c * NPTS + n]; s += v * v; }
    sq[i] = s;
}

// ---------------- euclid knn v2: wave-per-query, 4 queries/block, barrier-free ----------------
__global__ __launch_bounds__(256) void k_knn_euclid(const float* __restrict__ x,
                                                    const float* __restrict__ sq,
                                                    int* __restrict__ idx) {
    __shared__ float dw[4][NPTS];    // 64 KB, wave-private rows
    int t = threadIdx.x;
    int w = t >> 6, ln = t & 63;
    int qid = blockIdx.x * 4 + w;    // global query id
    int b = qid >> 12, qn = qid & 4095;
    const float* xb = x + b * 6 * NPTS;
    const float* sqb = sq + b * NPTS;
    // query vector: broadcast loads (uniform)
    float q0 = xb[qn], q1 = xb[NPTS + qn], q2 = xb[2 * NPTS + qn];
    float q3 = xb[3 * NPTS + qn], q4 = xb[4 * NPTS + qn], q5 = xb[5 * NPTS + qn];
    float sqn = sqb[qn];
    // distances (same formula as verified round-3 kernel)
    for (int j = 0; j < 64; j++) {
        int m = ln + (j << 6);
        float dot = q0 * xb[m] + q1 * xb[NPTS + m] + q2 * xb[2 * NPTS + m]
                  + q3 * xb[3 * NPTS + m] + q4 * xb[4 * NPTS + m] + q5 * xb[5 * NPTS + m];
        dw[w][m] = sqn - 2.f * dot + sqb[m];
    }
    // top-20 (min), wave-private scan — verified logic, no barrier needed (same wave)
    volatile float* dv = &dw[w][0];
    for (int kk = 0; kk < KNN; kk++) {
        float bv = FLT_MAX; int bm = NPTS;
        for (int j = 0; j < 64; j++) {
            int m = ln + (j << 6);
            float v = dv[m];
            if (v < bv) { bv = v; bm = m; }
        }
        for (int off = 32; off > 0; off >>= 1) {
            float ov = __shfl_down(bv, off);
            int   om = __shfl_down(bm, off);
            if (ov < bv || (ov == bv && om < bm)) { bv = ov; bm = om; }
        }
        bm = __shfl(bm, 0);
        if (ln == 0) { idx[qid * KNN + kk] = bm; dv[bm] = FLT_MAX; }
    }
}

// ---------------- cosine knn v2: wave-per-query, point-major normalized features ----------------
__global__ __launch_bounds__(256) void k_knn_cos(const float* __restrict__ xn,
                                                 int* __restrict__ idx) {
    __shared__ float dw[4][NPTS];    // 64 KB
    int t = threadIdx.x;
    int w = t >> 6, ln = t & 63;
    int qid = blockIdx.x * 4 + w;
    int b = qid >> 12;
    const float* xb = xn + (size_t)b * NPTS * 64;
    // query features -> registers (broadcast loads)
    float qr[64];
    const float* qp = xn + (size_t)qid * 64;
#pragma unroll
    for (int c4 = 0; c4 < 16; c4++) {
        float4 v = *(const float4*)(qp + c4 * 4);
        qr[c4 * 4 + 0] = v.x; qr[c4 * 4 + 1] = v.y; qr[c4 * 4 + 2] = v.z; qr[c4 * 4 + 3] = v.w;
    }
    for (int j = 0; j < 64; j++) {
        int m = ln + (j << 6);
        const float* cr = xb + (size_t)m * 64;
        float a0 = 0.f, a1 = 0.f, a2 = 0.f, a3 = 0.f;
#pragma unroll
        for (int c4 = 0; c4 < 16; c4++) {
            float4 v = *(const float4*)(cr + c4 * 4);
            a0 += qr[c4 * 4 + 0] * v.x; a1 += qr[c4 * 4 + 1] * v.y;
            a2 += qr[c4 * 4 + 2] * v.z; a3 += qr[c4 * 4 + 3] * v.w;
        }
        dw[w][m] = (a0 + a1) + (a2 + a3);
    }
    volatile float* dv = &dw[w][0];
    for (int kk = 0; kk < KNN; kk++) {
        float bv = -FLT_MAX; int bm = NPTS;
        for (int j = 0; j < 64; j++) {
            int m = ln + (j << 6);
            float v = dv[m];
            if (v > bv) { bv = v; bm = m; }
        }
        for (int off = 32; off > 0; off >>= 1) {
            float ov = __shfl_down(bv, off);
            int   om = __shfl_down(bm, off);
            if (ov > bv || (ov == bv && om < bm)) { bv = ov; bm = om; }
        }
        bm = __shfl(bm, 0);
        if (ln == 0) { idx[qid * KNN + kk] = bm; dv[bm] = -FLT_MAX; }
    }
}

// ---------------- normalize 64 cols of point-major xcpm -> point-major xn ----------------
__global__ void k_normalize(const float* __restrict__ xcpm, int coff, float* __restrict__ xn) {
    int pid = blockIdx.x * 256 + threadIdx.x;        // b*N + n
    const float* p = xcpm + (size_t)pid * 192 + coff;
    float s = 0.f;
#pragma unroll
    for (int c4 = 0; c4 < 16; c4++) {
        float4 v = *(const float4*)(p + c4 * 4);
        s += v.x * v.x + v.y * v.y + v.z * v.z + v.w * v.w;
    }
    float inv = 1.f / (sqrtf(s) + 1e-8f);
    float* q = xn + (size_t)pid * 64;
#pragma unroll
    for (int c4 = 0; c4 < 16; c4++) {
        float4 v = *(const float4*)(p + c4 * 4);
        float4 r; r.x = v.x * inv; r.y = v.y * inv; r.z = v.z * inv; r.w = v.w * inv;
        *(float4*)(q + c4 * 4) = r;
    }
}

// ---------------- EdgeConv 1: 6ch (channel-major x), 12->64->64, wave-per-point ----------------
__global__ __launch_bounds__(256) void k_edge1(const float* __restrict__ x,
    const float* __restrict__ w0, const float* __restrict__ s0, const float* __restrict__ o0,
    const float* __restrict__ w1, const float* __restrict__ s1, const float* __restrict__ o1,
    const int* __restrict__ idx, float* __restrict__ xcpm) {
    __shared__ float es[4][16];      // e vector (12 used), per wave
    __shared__ float h0s[4][64];
    int t = threadIdx.x;
    int w = t >> 6, o = t & 63;
    int pid = blockIdx.x * 4 + w;
    int b = pid >> 12, n = pid & 4095;
    const float* xb = x + b * 6 * NPTS;
    // weights in registers: w0 row (12), w1 row (64)
    float w0r[12];
    const float* w0p = w0 + o * 12;
#pragma unroll
    for (int c4 = 0; c4 < 3; c4++) {
        float4 v = *(const float4*)(w0p + c4 * 4);
        w0r[c4 * 4] = v.x; w0r[c4 * 4 + 1] = v.y; w0r[c4 * 4 + 2] = v.z; w0r[c4 * 4 + 3] = v.w;
    }
    float w1r[64];
    const float* w1p = w1 + o * 64;
#pragma unroll
    for (int c4 = 0; c4 < 16; c4++) {
        float4 v = *(const float4*)(w1p + c4 * 4);
        w1r[c4 * 4] = v.x; w1r[c4 * 4 + 1] = v.y; w1r[c4 * 4 + 2] = v.z; w1r[c4 * 4 + 3] = v.w;
    }
    float sv0 = s0[o], ov0 = o0[o], sv1 = s1[o], ov1 = o1[o];
    float cv = 0.f;
    if (o < 6) { cv = xb[o * NPTS + n]; es[w][6 + o] = cv; }
    if (o >= 12 && o < 16) es[w][o] = 0.f;   // pad lanes for b128 reads
    float acc = -FLT_MAX;
    const int* ib = idx + pid * KNN;
    for (int kk = 0; kk < KNN; kk++) {
        int j = ib[kk] & 4095;
        if (o < 6) es[w][o] = xb[o * NPTS + j] - cv;
        // h0[o] = dot(w0 row, e[0:12])  (same-wave LDS handoff, ds-order guarantees visibility)
        float h = 0.f;
#pragma unroll
        for (int c4 = 0; c4 < 3; c4++) {
            float4 e4 = *(const float4*)&es[w][c4 * 4];
            h += w0r[c4 * 4] * e4.x + w0r[c4 * 4 + 1] * e4.y + w0r[c4 * 4 + 2] * e4.z + w0r[c4 * 4 + 3] * e4.w;
        }
        h = lrelu(h * sv0 + ov0);
        h0s[w][o] = h;
        float h2 = 0.f;
#pragma unroll
        for (int c4 = 0; c4 < 16; c4++) {
            float4 h4 = *(const float4*)&h0s[w][c4 * 4];
            h2 += w1r[c4 * 4] * h4.x + w1r[c4 * 4 + 1] * h4.y + w1r[c4 * 4 + 2] * h4.z + w1r[c4 * 4 + 3] * h4.w;
        }
        h2 = lrelu(h2 * sv1 + ov1);
        acc = fmaxf(acc, h2);
    }
    xcpm[(size_t)pid * 192 + o] = acc;       // cols 0..63
}

// ---------------- EdgeConv 2/3: 64ch point-major gather, 128->64->64, wave-per-point ----------------
__global__ __launch_bounds__(256) void k_edge23(const float* __restrict__ xcpm,
    const float* __restrict__ w0, const float* __restrict__ s0, const float* __restrict__ o0,
    const float* __restrict__ w1, const float* __restrict__ s1, const float* __restrict__ o1,
    const int* __restrict__ idx, int ci, int co) {
    __shared__ float cs[4][64];
    __shared__ float es[4][64];
    __shared__ float h0s[4][64];
    int t = threadIdx.x;
    int w = t >> 6, o = t & 63;
    int pid = blockIdx.x * 4 + w;
    int b = pid >> 12;
    // weights in registers: w0 first-half row (64), w1 row (64)
    float w0r[64];
    const float* w0p = w0 + o * 128;
#pragma unroll
    for (int c4 = 0; c4 < 16; c4++) {
        float4 v = *(const float4*)(w0p + c4 * 4);
        w0r[c4 * 4] = v.x; w0r[c4 * 4 + 1] = v.y; w0r[c4 * 4 + 2] = v.z; w0r[c4 * 4 + 3] = v.w;
    }
    float w1r[64];
    const float* w1p = w1 + o * 64;
#pragma unroll
    for (int c4 = 0; c4 < 16; c4++) {
        float4 v = *(const float4*)(w1p + c4 * 4);
        w1r[c4 * 4] = v.x; w1r[c4 * 4 + 1] = v.y; w1r[c4 * 4 + 2] = v.z; w1r[c4 * 4 + 3] = v.w;
    }
    float sv0 = s0[o], ov0 = o0[o], sv1 = s1[o], ov1 = o1[o];
    float cv = xcpm[(size_t)pid * 192 + ci + o];
    cs[w][o] = cv;
    // k-invariant part: h0base[o] = sum_c w0[o][64+c] * ctr[c]
    float h0b = 0.f;
    const float* w0q = w0p + 64;
#pragma unroll
    for (int c4 = 0; c4 < 16; c4++) {
        float4 wv = *(const float4*)(w0q + c4 * 4);
        float4 c4v = *(const float4*)&cs[w][c4 * 4];
        h0b += wv.x * c4v.x + wv.y * c4v.y + wv.z * c4v.z + wv.w * c4v.w;
    }
    float acc = -FLT_MAX;
    const int* ib = idx + pid * KNN;
    for (int kk = 0; kk < KNN; kk++) {
        int j = ib[kk] & 4095;
        float nv = xcpm[((size_t)(b * 4096 + j)) * 192 + ci + o];   // coalesced 256B gather
        es[w][o] = nv - cv;
        float h = h0b;
#pragma unroll
        for (int c4 = 0; c4 < 16; c4++) {
            float4 e4 = *(const float4*)&es[w][c4 * 4];
            h += w0r[c4 * 4] * e4.x + w0r[c4 * 4 + 1] * e4.y + w0r[c4 * 4 + 2] * e4.z + w0r[c4 * 4 + 3] * e4.w;
        }
        h = lrelu(h * sv0 + ov0);
        h0s[w][o] = h;
        float h2 = 0.f;
#pragma unroll
        for (int c4 = 0; c4 < 16; c4++) {
            float4 h4 = *(const float4*)&h0s[w][c4 * 4];
            h2 += w1r[c4 * 4] * h4.x + w1r[c4 * 4 + 1] * h4.y + w1r[c4 * 4 + 2] * h4.z + w1r[c4 * 4 + 3] * h4.w;
        }
        h2 = lrelu(h2 * sv1 + ov1);
        acc = fmaxf(acc, h2);
    }
    float* outp = (float*)xcpm;      // write distinct cols; const-cast for single param
    outp[(size_t)pid * 192 + co + o] = acc;
}

// ---------------- init g to -inf ----------------
__global__ void k_init_g(float* __restrict__ g) {
    g[blockIdx.x * 256 + threadIdx.x] = -FLT_MAX;
}

// ---------------- conv w4 (192->1024) + fused global max pool, point-major xc ----------------
__global__ __launch_bounds__(256) void k_w4pool(const float* __restrict__ xc,
                                                const float* __restrict__ w4,
                                                const float* __restrict__ b4,
                                                float* __restrict__ g) {
    __shared__ float wl[16][192];    // 12 KB
    __shared__ float bl[16];
    int t = threadIdx.x;
    int obase = blockIdx.y * 16, b = blockIdx.z;
    for (int i = t; i < 16 * 192; i += 256) { int oo = i / 192, c = i - oo * 192; wl[oo][c] = w4[(obase + oo) * 192 + c]; }
    if (t < 16) bl[t] = b4[obase + t];
    __syncthreads();
    int n = blockIdx.x * 256 + t;
    const float* xr = xc + (size_t)(b * 4096 + n) * 192;
    float acc[16];
#pragma unroll
    for (int oo = 0; oo < 16; oo++) acc[oo] = 0.f;
    for (int c4 = 0; c4 < 48; c4++) {
        float4 xv = *(const float4*)(xr + c4 * 4);
#pragma unroll
        for (int oo = 0; oo < 16; oo++) {
            float4 wv = *(const float4*)&wl[oo][c4 * 4];
            acc[oo] += wv.x * xv.x + wv.y * xv.y + wv.z * xv.z + wv.w * xv.w;
        }
    }
#pragma unroll
    for (int oo = 0; oo < 16; oo++) {
        float h = lrelu(acc[oo] + bl[oo]);
        for (int off = 32; off > 0; off >>= 1) h = fmaxf(h, __shfl_down(h, off));
        if ((t & 63) == 0) atomicMaxF(&g[b * 1024 + obase + oo], h);
    }
}

// ---------------- goff[b][o] = (wf1[o,192:1216] . g[b]) * sf1[o] + of1[o] ----------------
__global__ __launch_bounds__(256) void k_goff(const float* __restrict__ g,
                                              const float* __restrict__ wf1,
                                              const float* __restrict__ sf1,
                                              const float* __restrict__ of1,
                                              float* __restrict__ goff) {
    int bo = blockIdx.x;                 // b*512 + o
    int b = bo >> 9, o = bo & 511;
    int t = threadIdx.x;
    const float* wr = wf1 + (size_t)o * 1216 + 192;
    const float* gb = g + b * 1024;
    float s = 0.f;
    for (int c = t; c < 1024; c += 256) s += wr[c] * gb[c];
    __shared__ float red[4];
    for (int off = 32; off > 0; off >>= 1) s += __shfl_down(s, off);
    if ((t & 63) == 0) red[t >> 6] = s;
    __syncthreads();
    if (t == 0) {
        float tot = red[0] + red[1] + red[2] + red[3];
        goff[bo] = tot * sf1[o] + of1[o];
    }
}

// ---------------- fused tail: h1(512) -> h2(256) -> out(13) per 16-point tile ----------------
#define TN 16
__global__ __launch_bounds__(256) void k_tail(const float* __restrict__ xc,
                                              const float* __restrict__ wf1,
                                              const float* __restrict__ sf1,
                                              const float* __restrict__ goff,
                                              const float* __restrict__ wf2,
                                              const float* __restrict__ sf2,
                                              const float* __restrict__ of2,
                                              const float* __restrict__ wf3,
                                              float* __restrict__ out) {
    __shared__ float xcs[192][17];       // 13 KB (pad 17 breaks staging bank conflicts)
    __shared__ float h1s[512][17];       // 34.8 KB
    __shared__ float h2s[256][17];       // 17.4 KB
    int t = threadIdx.x;
    int b = blockIdx.y;
    int n0 = blockIdx.x * TN;
    const float* xb = xc + (size_t)(b * 4096 + n0) * 192;
    // stage 16 points x 192 ch from point-major, transposing into [c][tn]
    for (int i = t; i < 768; i += 256) {           // 768 float4 loads
        int pt = i / 48, c4 = i - pt * 48;
        float4 v = *(const float4*)(xb + pt * 192 + c4 * 4);
        xcs[c4 * 4 + 0][pt] = v.x; xcs[c4 * 4 + 1][pt] = v.y;
        xcs[c4 * 4 + 2][pt] = v.z; xcs[c4 * 4 + 3][pt] = v.w;
    }
    __syncthreads();
    // h1: 512 outputs, 2 per thread
#pragma unroll
    for (int oo = 0; oo < 2; oo++) {
        int o = oo * 256 + t;
        const float* wr = wf1 + (size_t)o * 1216;
        float s = sf1[o];
        float gofv = goff[b * 512 + o];
        float acc[TN];
#pragma unroll
        for (int tn = 0; tn < TN; tn++) acc[tn] = 0.f;
        for (int c4 = 0; c4 < 48; c4++) {
            float4 wv = *(const float4*)(wr + c4 * 4);
#pragma unroll
            for (int tn = 0; tn < TN; tn++)
                acc[tn] += wv.x * xcs[c4 * 4][tn] + wv.y * xcs[c4 * 4 + 1][tn]
                         + wv.z * xcs[c4 * 4 + 2][tn] + wv.w * xcs[c4 * 4 + 3][tn];
        }
#pragma unroll
        for (int tn = 0; tn < TN; tn++) h1s[o][tn] = lrelu(acc[tn] * s + gofv);
    }
    __syncthreads();
    // h2: 256 outputs, 1 per thread
    {
        int o = t;
        const float* wr = wf2 + o * 512;
        float s = sf2[o], of = of2[o];
        float acc[TN];
#pragma unroll
        for (int tn = 0; tn < TN; tn++) acc[tn] = 0.f;
        for (int c4 = 0; c4 < 128; c4++) {
            float4 wv = *(const float4*)(wr + c4 * 4);
#pragma unroll
            for (int tn = 0; tn < TN; tn++)
                acc[tn] += wv.x * h1s[c4 * 4][tn] + wv.y * h1s[c4 * 4 + 1][tn]
                         + wv.z * h1s[c4 * 4 + 2][tn] + wv.w * h1s[c4 * 4 + 3][tn];
        }
#pragma unroll
        for (int tn = 0; tn < TN; tn++) h2s[o][tn] = lrelu(acc[tn] * s + of);
    }
    __syncthreads();
    // out: 13 x 16
    if (t < 13 * TN) {
        int o = t >> 4, tn = t & 15;
        const float* wr = wf3 + o * 256;
        float acc = 0.f;
        for (int c4 = 0; c4 < 64; c4++) {
            float4 wv = *(const float4*)(wr + c4 * 4);
            acc += wv.x * h2s[c4 * 4][tn] + wv.y * h2s[c4 * 4 + 1][tn]
                 + wv.z * h2s[c4 * 4 + 2][tn] + wv.w * h2s[c4 * 4 + 3][tn];
        }
        out[((size_t)b * 13 + o) * NPTS + n0 + tn] = acc;
    }
}

extern "C" void kernel_launch(void* const* d_in, const int* in_sizes, int n_in,
                              void* d_out, int out_size, void* d_ws, size_t ws_size,
                              hipStream_t stream) {
    const float* x    = (const float*)d_in[0];
    const float* w1_0 = (const float*)d_in[1];
    const float* s1_0 = (const float*)d_in[2];
    const float* o1_0 = (const float*)d_in[3];
    const float* w1_1 = (const float*)d_in[4];
    const float* s1_1 = (const float*)d_in[5];
    const float* o1_1 = (const float*)d_in[6];
    const float* w2_0 = (const float*)d_in[7];
    const float* s2_0 = (const float*)d_in[8];
    const float* o2_0 = (const float*)d_in[9];
    const float* w2_1 = (const float*)d_in[10];
    const float* s2_1 = (const float*)d_in[11];
    const float* o2_1 = (const float*)d_in[12];
    const float* w3_0 = (const float*)d_in[13];
    const float* s3_0 = (const float*)d_in[14];
    const float* o3_0 = (const float*)d_in[15];
    const float* w3_1 = (const float*)d_in[16];
    const float* s3_1 = (const float*)d_in[17];
    const float* o3_1 = (const float*)d_in[18];
    const float* w4   = (const float*)d_in[19];
    const float* b4   = (const float*)d_in[20];
    const float* wf1  = (const float*)d_in[21];
    const float* sf1  = (const float*)d_in[22];
    const float* of1  = (const float*)d_in[23];
    const float* wf2  = (const float*)d_in[24];
    const float* sf2  = (const float*)d_in[25];
    const float* of2  = (const float*)d_in[26];
    const float* wf3  = (const float*)d_in[27];
    // d_in[28] = k (int, always 20)

    // workspace layout (floats) — total ~18.2 MB (same footprint as passing round 3)
    float* xcpm = (float*)d_ws;                             // B*N*192 point-major = 3,145,728 f
    float* xn   = xcpm + (size_t)NB * NPTS * 192;           // B*N*64 point-major  = 1,048,576 f
    float* sq   = xn + (size_t)NB * NPTS * 64;              // B*N     = 16,384 f
    float* g    = sq + NB * NPTS;                           // B*1024  = 4,096 f
    float* goff = g + NB * 1024;                            // B*512   = 2,048 f
    int*   idx  = (int*)(goff + NB * 512);                  // B*N*20  = 327,680 i
    (void)in_sizes; (void)n_in; (void)out_size; (void)ws_size;

    k_sqnorm<<<NB * NPTS / 256, 256, 0, stream>>>(x, sq);
    k_knn_euclid<<<NB * NPTS / 4, 256, 0, stream>>>(x, sq, idx);
    k_edge1<<<NB * NPTS / 4, 256, 0, stream>>>(x, w1_0, s1_0, o1_0, w1_1, s1_1, o1_1, idx, xcpm);
    k_normalize<<<NB * NPTS / 256, 256, 0, stream>>>(xcpm, 0, xn);
    k_knn_cos<<<NB * NPTS / 4, 256, 0, stream>>>(xn, idx);
    k_edge23<<<NB * NPTS / 4, 256, 0, stream>>>(xcpm, w2_0, s2_0, o2_0, w2_1, s2_1, o2_1, idx, 0, 64);
    k_normalize<<<NB * NPTS / 256, 256, 0, stream>>>(xcpm, 64, xn);
    k_knn_cos<<<NB * NPTS / 4, 256, 0, stream>>>(xn, idx);
    k_edge23<<<NB * NPTS / 4, 256, 0, stream>>>(xcpm, w3_0, s3_0, o3_0, w3_1, s3_1, o3_1, idx, 64, 128);
    k_init_g<<<NB * 1024 / 256, 256, 0, stream>>>(g);
    k_w4pool<<<dim3(16, 64, NB), 256, 0, stream>>>(xcpm, w4, b4, g);
    k_goff<<<NB * 512, 256, 0, stream>>>(g, wf1, sf1, of1, goff);
    k_tail<<<dim3(NPTS / TN, NB), 256, 0, stream>>>(xcpm, wf1, sf1, goff, wf2, sf2, of2, wf3, (float*)d_out);
}

// Round 5
// 3243.679 us; speedup vs baseline: 1.8080x; 1.8080x over previous
//
#include <hip/hip_runtime.h>
#include <hip/hip_bf16.h>
#include <float.h>

#define NPTS 4096
#define NB 4
#define KNN 20

__device__ __forceinline__ float lrelu(float x) { return x > 0.f ? x : 0.2f * x; }

__device__ __forceinline__ void atomicMaxF(float* addr, float val) {
    int* ia = (int*)addr;
    int old = *ia;
    while (__int_as_float(old) < val) {
        int assumed = old;
        old = atomicCAS(ia, assumed, __float_as_int(val));
        if (old == assumed) break;
    }
}

// ---------------- sq norms for euclid knn (channel-major x, coalesced) ----------------
__global__ void k_sqnorm(const float* __restrict__ x, float* __restrict__ sq) {
    int i = blockIdx.x * 256 + threadIdx.x;   // b*N + n
    int b = i >> 12, n = i & 4095;
    const float* xb = x + b * 6 * NPTS;
    float s = 0.f;
#pragma unroll
    for (int c = 0; c < 6; c++) { float v = xb[c * NPTS + n]; s += v * v; }
    sq[i] = s;
}

// ---------------- euclid knn: wave-per-query, 4 queries/block, barrier-free ----------------
__global__ __launch_bounds__(256) void k_knn_euclid(const float* __restrict__ x,
                                                    const float* __restrict__ sq,
                                                    int* __restrict__ idx) {
    __shared__ float dw[4][NPTS];    // 64 KB, wave-private rows
    int t = threadIdx.x;
    int w = t >> 6, ln = t & 63;
    int qid = blockIdx.x * 4 + w;    // global query id
    int b = qid >> 12, qn = qid & 4095;
    const float* xb = x + b * 6 * NPTS;
    const float* sqb = sq + b * NPTS;
    float q0 = xb[qn], q1 = xb[NPTS + qn], q2 = xb[2 * NPTS + qn];
    float q3 = xb[3 * NPTS + qn], q4 = xb[4 * NPTS + qn], q5 = xb[5 * NPTS + qn];
    float sqn = sqb[qn];
    for (int j = 0; j < 64; j++) {
        int m = ln + (j << 6);
        float dot = q0 * xb[m] + q1 * xb[NPTS + m] + q2 * xb[2 * NPTS + m]
                  + q3 * xb[3 * NPTS + m] + q4 * xb[4 * NPTS + m] + q5 * xb[5 * NPTS + m];
        dw[w][m] = sqn - 2.f * dot + sqb[m];
    }
    volatile float* dv = &dw[w][0];
    for (int kk = 0; kk < KNN; kk++) {
        float bv = FLT_MAX; int bm = NPTS;
        for (int j = 0; j < 64; j++) {
            int m = ln + (j << 6);
            float v = dv[m];
            if (v < bv) { bv = v; bm = m; }
        }
        for (int off = 32; off > 0; off >>= 1) {
            float ov = __shfl_down(bv, off);
            int   om = __shfl_down(bm, off);
            if (ov < bv || (ov == bv && om < bm)) { bv = ov; bm = om; }
        }
        bm = __shfl(bm, 0);
        if (ln == 0) { idx[qid * KNN + kk] = bm; dv[bm] = FLT_MAX; }
    }
}

// ---------------- cosine knn v3: LDS candidate tiles + streaming distributed top-20 ----------------
__global__ __launch_bounds__(256) void k_knn_cos(const float* __restrict__ xn,
                                                 int* __restrict__ idx) {
    __shared__ float cs[64][129];    // channel-major tile: 64 ch x 128 cand, pad->129 (33 KB)
    int t = threadIdx.x;
    int w = t >> 6, ln = t & 63;
    int b = blockIdx.x >> 10;                  // 1024 blocks per batch
    int qn = (blockIdx.x & 1023) * 4 + w;
    int qid = (b << 12) + qn;
    const float* xb = xn + (((size_t)b) << 12) * 64;
    // query -> registers (wave-uniform broadcast loads)
    float qr[64];
    const float* qp = xn + (size_t)qid * 64;
#pragma unroll
    for (int c4 = 0; c4 < 16; c4++) {
        float4 v = *(const float4*)(qp + c4 * 4);
        qr[c4 * 4] = v.x; qr[c4 * 4 + 1] = v.y; qr[c4 * 4 + 2] = v.z; qr[c4 * 4 + 3] = v.w;
    }
    // distributed top-20: lane i (i<20) holds i-th best (val desc, ties lower idx first)
    float lv = -FLT_MAX; int li = 0x7fffffff;
    float thresh = -FLT_MAX;
    for (int tile = 0; tile < 32; tile++) {
        int t0 = tile << 7;
        __syncthreads();                       // prior compute done before restage
        // stage 128 cand x 64 ch, coalesced rows -> channel-major LDS
#pragma unroll
        for (int r = 0; r < 8; r++) {
            int f = t + (r << 8);              // float4 id 0..2047
            int row = f >> 4, q = f & 15;
            float4 v = *(const float4*)(xb + (size_t)(t0 + row) * 64 + q * 4);
            cs[q * 4 + 0][row] = v.x; cs[q * 4 + 1][row] = v.y;
            cs[q * 4 + 2][row] = v.z; cs[q * 4 + 3][row] = v.w;
        }
        __syncthreads();
        // sims for candidates t0+ln and t0+64+ln (2-way bank alias = free)
        float a0 = 0.f, a1 = 0.f, b0 = 0.f, b1 = 0.f;
#pragma unroll
        for (int c = 0; c < 64; c += 2) {
            a0 += qr[c] * cs[c][ln];        a1 += qr[c + 1] * cs[c + 1][ln];
            b0 += qr[c] * cs[c][64 + ln];   b1 += qr[c + 1] * cs[c + 1][64 + ln];
        }
        float sim0 = a0 + a1, sim1 = b0 + b1;
        // insert accepted candidates in increasing index order
#pragma unroll
        for (int gsel = 0; gsel < 2; gsel++) {
            float sv = gsel ? sim1 : sim0;
            int base = t0 + (gsel << 6);
            unsigned long long mask = __ballot(sv > thresh);
            while (mask) {
                int src = __ffsll((unsigned long long)mask) - 1;
                mask &= mask - 1;
                float v = __shfl(sv, src);
                if (!(v > thresh)) continue;   // wave-uniform recheck vs updated thresh
                int mi = base + src;
                float pv = __shfl_up(lv, 1);
                int   pi = __shfl_up(li, 1);
                unsigned long long bm = __ballot(ln < 20 && lv >= v);  // >=: equal keeps earlier (lower idx)
                int pos = __popcll(bm);
                if (ln < 20) {
                    if (ln == pos) { lv = v; li = mi; }
                    else if (ln > pos) { lv = pv; li = pi; }
                }
                thresh = __shfl(lv, 19);
            }
        }
    }
    if (ln < KNN) idx[(size_t)qid * KNN + ln] = li;
}

// ---------------- normalize 64 cols of point-major xcpm -> point-major xn ----------------
__global__ void k_normalize(const float* __restrict__ xcpm, int coff, float* __restrict__ xn) {
    int pid = blockIdx.x * 256 + threadIdx.x;        // b*N + n
    const float* p = xcpm + (size_t)pid * 192 + coff;
    float s = 0.f;
#pragma unroll
    for (int c4 = 0; c4 < 16; c4++) {
        float4 v = *(const float4*)(p + c4 * 4);
        s += v.x * v.x + v.y * v.y + v.z * v.z + v.w * v.w;
    }
    float inv = 1.f / (sqrtf(s) + 1e-8f);
    float* q = xn + (size_t)pid * 64;
#pragma unroll
    for (int c4 = 0; c4 < 16; c4++) {
        float4 v = *(const float4*)(p + c4 * 4);
        float4 r; r.x = v.x * inv; r.y = v.y * inv; r.z = v.z * inv; r.w = v.w * inv;
        *(float4*)(q + c4 * 4) = r;
    }
}

// ---------------- EdgeConv 1: 6ch (channel-major x), 12->64->64, wave-per-point ----------------
__global__ __launch_bounds__(256) void k_edge1(const float* __restrict__ x,
    const float* __restrict__ w0, const float* __restrict__ s0, const float* __restrict__ o0,
    const float* __restrict__ w1, const float* __restrict__ s1, const float* __restrict__ o1,
    const int* __restrict__ idx, float* __restrict__ xcpm) {
    __shared__ float es[4][16];      // e vector (12 used), per wave
    __shared__ float h0s[4][64];
    int t = threadIdx.x;
    int w = t >> 6, o = t & 63;
    int pid = blockIdx.x * 4 + w;
    int b = pid >> 12, n = pid & 4095;
    const float* xb = x + b * 6 * NPTS;
    float w0r[12];
    const float* w0p = w0 + o * 12;
#pragma unroll
    for (int c4 = 0; c4 < 3; c4++) {
        float4 v = *(const float4*)(w0p + c4 * 4);
        w0r[c4 * 4] = v.x; w0r[c4 * 4 + 1] = v.y; w0r[c4 * 4 + 2] = v.z; w0r[c4 * 4 + 3] = v.w;
    }
    float w1r[64];
    const float* w1p = w1 + o * 64;
#pragma unroll
    for (int c4 = 0; c4 < 16; c4++) {
        float4 v = *(const float4*)(w1p + c4 * 4);
        w1r[c4 * 4] = v.x; w1r[c4 * 4 + 1] = v.y; w1r[c4 * 4 + 2] = v.z; w1r[c4 * 4 + 3] = v.w;
    }
    float sv0 = s0[o], ov0 = o0[o], sv1 = s1[o], ov1 = o1[o];
    float cv = 0.f;
    if (o < 6) { cv = xb[o * NPTS + n]; es[w][6 + o] = cv; }
    if (o >= 12 && o < 16) es[w][o] = 0.f;   // pad lanes for b128 reads
    float acc = -FLT_MAX;
    const int* ib = idx + pid * KNN;
    for (int kk = 0; kk < KNN; kk++) {
        int j = ib[kk] & 4095;
        if (o < 6) es[w][o] = xb[o * NPTS + j] - cv;
        float h = 0.f;
#pragma unroll
        for (int c4 = 0; c4 < 3; c4++) {
            float4 e4 = *(const float4*)&es[w][c4 * 4];
            h += w0r[c4 * 4] * e4.x + w0r[c4 * 4 + 1] * e4.y + w0r[c4 * 4 + 2] * e4.z + w0r[c4 * 4 + 3] * e4.w;
        }
        h = lrelu(h * sv0 + ov0);
        h0s[w][o] = h;
        float h2 = 0.f;
#pragma unroll
        for (int c4 = 0; c4 < 16; c4++) {
            float4 h4 = *(const float4*)&h0s[w][c4 * 4];
            h2 += w1r[c4 * 4] * h4.x + w1r[c4 * 4 + 1] * h4.y + w1r[c4 * 4 + 2] * h4.z + w1r[c4 * 4 + 3] * h4.w;
        }
        h2 = lrelu(h2 * sv1 + ov1);
        acc = fmaxf(acc, h2);
    }
    xcpm[(size_t)pid * 192 + o] = acc;       // cols 0..63
}

// ---------------- EdgeConv 2/3: 64ch point-major gather, 128->64->64, wave-per-point ----------------
__global__ __launch_bounds__(256) void k_edge23(const float* __restrict__ xcpm,
    const float* __restrict__ w0, const float* __restrict__ s0, const float* __restrict__ o0,
    const float* __restrict__ w1, const float* __restrict__ s1, const float* __restrict__ o1,
    const int* __restrict__ idx, int ci, int co) {
    __shared__ float cs[4][64];
    __shared__ float es[4][64];
    __shared__ float h0s[4][64];
    int t = threadIdx.x;
    int w = t >> 6, o = t & 63;
    int pid = blockIdx.x * 4 + w;
    int b = pid >> 12;
    float w0r[64];
    const float* w0p = w0 + o * 128;
#pragma unroll
    for (int c4 = 0; c4 < 16; c4++) {
        float4 v = *(const float4*)(w0p + c4 * 4);
        w0r[c4 * 4] = v.x; w0r[c4 * 4 + 1] = v.y; w0r[c4 * 4 + 2] = v.z; w0r[c4 * 4 + 3] = v.w;
    }
    float w1r[64];
    const float* w1p = w1 + o * 64;
#pragma unroll
    for (int c4 = 0; c4 < 16; c4++) {
        float4 v = *(const float4*)(w1p + c4 * 4);
        w1r[c4 * 4] = v.x; w1r[c4 * 4 + 1] = v.y; w1r[c4 * 4 + 2] = v.z; w1r[c4 * 4 + 3] = v.w;
    }
    float sv0 = s0[o], ov0 = o0[o], sv1 = s1[o], ov1 = o1[o];
    float cv = xcpm[(size_t)pid * 192 + ci + o];
    cs[w][o] = cv;
    float h0b = 0.f;
    const float* w0q = w0p + 64;
#pragma unroll
    for (int c4 = 0; c4 < 16; c4++) {
        float4 wv = *(const float4*)(w0q + c4 * 4);
        float4 c4v = *(const float4*)&cs[w][c4 * 4];
        h0b += wv.x * c4v.x + wv.y * c4v.y + wv.z * c4v.z + wv.w * c4v.w;
    }
    float acc = -FLT_MAX;
    const int* ib = idx + pid * KNN;
    for (int kk = 0; kk < KNN; kk++) {
        int j = ib[kk] & 4095;
        float nv = xcpm[((size_t)(b * 4096 + j)) * 192 + ci + o];   // coalesced 256B gather
        es[w][o] = nv - cv;
        float h = h0b;
#pragma unroll
        for (int c4 = 0; c4 < 16; c4++) {
            float4 e4 = *(const float4*)&es[w][c4 * 4];
            h += w0r[c4 * 4] * e4.x + w0r[c4 * 4 + 1] * e4.y + w0r[c4 * 4 + 2] * e4.z + w0r[c4 * 4 + 3] * e4.w;
        }
        h = lrelu(h * sv0 + ov0);
        h0s[w][o] = h;
        float h2 = 0.f;
#pragma unroll
        for (int c4 = 0; c4 < 16; c4++) {
            float4 h4 = *(const float4*)&h0s[w][c4 * 4];
            h2 += w1r[c4 * 4] * h4.x + w1r[c4 * 4 + 1] * h4.y + w1r[c4 * 4 + 2] * h4.z + w1r[c4 * 4 + 3] * h4.w;
        }
        h2 = lrelu(h2 * sv1 + ov1);
        acc = fmaxf(acc, h2);
    }
    float* outp = (float*)xcpm;
    outp[(size_t)pid * 192 + co + o] = acc;
}

// ---------------- init g to -inf ----------------
__global__ void k_init_g(float* __restrict__ g) {
    g[blockIdx.x * 256 + threadIdx.x] = -FLT_MAX;
}

// ---------------- conv w4 (192->1024) + fused global max pool, point-major xc ----------------
__global__ __launch_bounds__(256) void k_w4pool(const float* __restrict__ xc,
                                                const float* __restrict__ w4,
                                                const float* __restrict__ b4,
                                                float* __restrict__ g) {
    __shared__ float wl[16][192];    // 12 KB
    __shared__ float bl[16];
    int t = threadIdx.x;
    int obase = blockIdx.y * 16, b = blockIdx.z;
    for (int i = t; i < 16 * 192; i += 256) { int oo = i / 192, c = i - oo * 192; wl[oo][c] = w4[(obase + oo) * 192 + c]; }
    if (t < 16) bl[t] = b4[obase + t];
    __syncthreads();
    int n = blockIdx.x * 256 + t;
    const float* xr = xc + (size_t)(b * 4096 + n) * 192;
    float acc[16];
#pragma unroll
    for (int oo = 0; oo < 16; oo++) acc[oo] = 0.f;
    for (int c4 = 0; c4 < 48; c4++) {
        float4 xv = *(const float4*)(xr + c4 * 4);
#pragma unroll
        for (int oo = 0; oo < 16; oo++) {
            float4 wv = *(const float4*)&wl[oo][c4 * 4];
            acc[oo] += wv.x * xv.x + wv.y * xv.y + wv.z * xv.z + wv.w * xv.w;
        }
    }
#pragma unroll
    for (int oo = 0; oo < 16; oo++) {
        float h = lrelu(acc[oo] + bl[oo]);
        for (int off = 32; off > 0; off >>= 1) h = fmaxf(h, __shfl_down(h, off));
        if ((t & 63) == 0) atomicMaxF(&g[b * 1024 + obase + oo], h);
    }
}

// ---------------- goff[b][o] = (wf1[o,192:1216] . g[b]) * sf1[o] + of1[o] ----------------
__global__ __launch_bounds__(256) void k_goff(const float* __restrict__ g,
                                              const float* __restrict__ wf1,
                                              const float* __restrict__ sf1,
                                              const float* __restrict__ of1,
                                              float* __restrict__ goff) {
    int bo = blockIdx.x;                 // b*512 + o
    int b = bo >> 9, o = bo & 511;
    int t = threadIdx.x;
    const float* wr = wf1 + (size_t)o * 1216 + 192;
    const float* gb = g + b * 1024;
    float s = 0.f;
    for (int c = t; c < 1024; c += 256) s += wr[c] * gb[c];
    __shared__ float red[4];
    for (int off = 32; off > 0; off >>= 1) s += __shfl_down(s, off);
    if ((t & 63) == 0) red[t >> 6] = s;
    __syncthreads();
    if (t == 0) {
        float tot = red[0] + red[1] + red[2] + red[3];
        goff[bo] = tot * sf1[o] + of1[o];
    }
}

// ---------------- fused tail: h1(512) -> h2(256) -> out(13) per 16-point tile ----------------
#define TN 16
__global__ __launch_bounds__(256) void k_tail(const float* __restrict__ xc,
                                              const float* __restrict__ wf1,
                                              const float* __restrict__ sf1,
                                              const float* __restrict__ goff,
                                              const float* __restrict__ wf2,
                                              const float* __restrict__ sf2,
                                              const float* __restrict__ of2,
                                              const float* __restrict__ wf3,
                                              float* __restrict__ out) {
    __shared__ float xcs[192][17];       // 13 KB
    __shared__ float h1s[512][17];       // 34.8 KB
    __shared__ float h2s[256][17];       // 17.4 KB
    int t = threadIdx.x;
    int b = blockIdx.y;
    int n0 = blockIdx.x * TN;
    const float* xb = xc + (size_t)(b * 4096 + n0) * 192;
    for (int i = t; i < 768; i += 256) {
        int pt = i / 48, c4 = i - pt * 48;
        float4 v = *(const float4*)(xb + pt * 192 + c4 * 4);
        xcs[c4 * 4 + 0][pt] = v.x; xcs[c4 * 4 + 1][pt] = v.y;
        xcs[c4 * 4 + 2][pt] = v.z; xcs[c4 * 4 + 3][pt] = v.w;
    }
    __syncthreads();
#pragma unroll
    for (int oo = 0; oo < 2; oo++) {
        int o = oo * 256 + t;
        const float* wr = wf1 + (size_t)o * 1216;
        float s = sf1[o];
        float gofv = goff[b * 512 + o];
        float acc[TN];
#pragma unroll
        for (int tn = 0; tn < TN; tn++) acc[tn] = 0.f;
        for (int c4 = 0; c4 < 48; c4++) {
            float4 wv = *(const float4*)(wr + c4 * 4);
#pragma unroll
            for (int tn = 0; tn < TN; tn++)
                acc[tn] += wv.x * xcs[c4 * 4][tn] + wv.y * xcs[c4 * 4 + 1][tn]
                         + wv.z * xcs[c4 * 4 + 2][tn] + wv.w * xcs[c4 * 4 + 3][tn];
        }
#pragma unroll
        for (int tn = 0; tn < TN; tn++) h1s[o][tn] = lrelu(acc[tn] * s + gofv);
    }
    __syncthreads();
    {
        int o = t;
        const float* wr = wf2 + o * 512;
        float s = sf2[o], of = of2[o];
        float acc[TN];
#pragma unroll
        for (int tn = 0; tn < TN; tn++) acc[tn] = 0.f;
        for (int c4 = 0; c4 < 128; c4++) {
            float4 wv = *(const float4*)(wr + c4 * 4);
#pragma unroll
            for (int tn = 0; tn < TN; tn++)
                acc[tn] += wv.x * h1s[c4 * 4][tn] + wv.y * h1s[c4 * 4 + 1][tn]
                         + wv.z * h1s[c4 * 4 + 2][tn] + wv.w * h1s[c4 * 4 + 3][tn];
        }
#pragma unroll
        for (int tn = 0; tn < TN; tn++) h2s[o][tn] = lrelu(acc[tn] * s + of);
    }
    __syncthreads();
    if (t < 13 * TN) {
        int o = t >> 4, tn = t & 15;
        const float* wr = wf3 + o * 256;
        float acc = 0.f;
        for (int c4 = 0; c4 < 64; c4++) {
            float4 wv = *(const float4*)(wr + c4 * 4);
            acc += wv.x * h2s[c4 * 4][tn] + wv.y * h2s[c4 * 4 + 1][tn]
                 + wv.z * h2s[c4 * 4 + 2][tn] + wv.w * h2s[c4 * 4 + 3][tn];
        }
        out[((size_t)b * 13 + o) * NPTS + n0 + tn] = acc;
    }
}

extern "C" void kernel_launch(void* const* d_in, const int* in_sizes, int n_in,
                              void* d_out, int out_size, void* d_ws, size_t ws_size,
                              hipStream_t stream) {
    const float* x    = (const float*)d_in[0];
    const float* w1_0 = (const float*)d_in[1];
    const float* s1_0 = (const float*)d_in[2];
    const float* o1_0 = (const float*)d_in[3];
    const float* w1_1 = (const float*)d_in[4];
    const float* s1_1 = (const float*)d_in[5];
    const float* o1_1 = (const float*)d_in[6];
    const float* w2_0 = (const float*)d_in[7];
    const float* s2_0 = (const float*)d_in[8];
    const float* o2_0 = (const float*)d_in[9];
    const float* w2_1 = (const float*)d_in[10];
    const float* s2_1 = (const float*)d_in[11];
    const float* o2_1 = (const float*)d_in[12];
    const float* w3_0 = (const float*)d_in[13];
    const float* s3_0 = (const float*)d_in[14];
    const float* o3_0 = (const float*)d_in[15];
    const float* w3_1 = (const float*)d_in[16];
    const float* s3_1 = (const float*)d_in[17];
    const float* o3_1 = (const float*)d_in[18];
    const float* w4   = (const float*)d_in[19];
    const float* b4   = (const float*)d_in[20];
    const float* wf1  = (const float*)d_in[21];
    const float* sf1  = (const float*)d_in[22];
    const float* of1  = (const float*)d_in[23];
    const float* wf2  = (const float*)d_in[24];
    const float* sf2  = (const float*)d_in[25];
    const float* of2  = (const float*)d_in[26];
    const float* wf3  = (const float*)d_in[27];
    // d_in[28] = k (int, always 20)

    // workspace layout (floats) — total ~18.2 MB
    float* xcpm = (float*)d_ws;                             // B*N*192 point-major
    float* xn   = xcpm + (size_t)NB * NPTS * 192;           // B*N*64 point-major
    float* sq   = xn + (size_t)NB * NPTS * 64;              // B*N
    float* g    = sq + NB * NPTS;                           // B*1024
    float* goff = g + NB * 1024;                            // B*512
    int*   idx  = (int*)(goff + NB * 512);                  // B*N*20
    (void)in_sizes; (void)n_in; (void)out_size; (void)ws_size;

    k_sqnorm<<<NB * NPTS / 256, 256, 0, stream>>>(x, sq);
    k_knn_euclid<<<NB * NPTS / 4, 256, 0, stream>>>(x, sq, idx);
    k_edge1<<<NB * NPTS / 4, 256, 0, stream>>>(x, w1_0, s1_0, o1_0, w1_1, s1_1, o1_1, idx, xcpm);
    k_normalize<<<NB * NPTS / 256, 256, 0, stream>>>(xcpm, 0, xn);
    k_knn_cos<<<NB * NPTS / 4, 256, 0, stream>>>(xn, idx);
    k_edge23<<<NB * NPTS / 4, 256, 0, stream>>>(xcpm, w2_0, s2_0, o2_0, w2_1, s2_1, o2_1, idx, 0, 64);
    k_normalize<<<NB * NPTS / 256, 256, 0, stream>>>(xcpm, 64, xn);
    k_knn_cos<<<NB * NPTS / 4, 256, 0, stream>>>(xn, idx);
    k_edge23<<<NB * NPTS / 4, 256, 0, stream>>>(xcpm, w3_0, s3_0, o3_0, w3_1, s3_1, o3_1, idx, 64, 128);
    k_init_g<<<NB * 1024 / 256, 256, 0, stream>>>(g);
    k_w4pool<<<dim3(16, 64, NB), 256, 0, stream>>>(xcpm, w4, b4, g);
    k_goff<<<NB * 512, 256, 0, stream>>>(g, wf1, sf1, of1, goff);
    k_tail<<<dim3(NPTS / TN, NB), 256, 0, stream>>>(xcpm, wf1, sf1, goff, wf2, sf2, of2, wf3, (float*)d_out);
}